// Round 10
// baseline (128.267 us; speedup 1.0000x reference)
//
#include <hip/hip_runtime.h>

// BaggingMaxPool: out[d] = mean_k( max_{r in indices[k,:]} inp[r][d] )
// N=1024 rows, D=100000 cols, K=20 rounds, SELECT_N=256.
//
// Round-10: PRODUCER/CONSUMER wave specialization over a persistent,
// double-buffered LDS column tile. Rounds 7-9 proved the round-major
// compute (idx u16-transposed in LDS, 16 entry-groups x 4 col-units,
// b128 tile reads, shfl_xor reduce) but stage & compute ran serially
// (~55us + ~60us). Here 256 persistent blocks (1/CU) x 512 threads:
// waves 0-3 compute tile t from buf[t&1] while waves 4-7 stage tile t+1
// into buf[t&1 ^ 1]; ONE barrier per tile. Finalize (cross-wave sum ->
// out) runs one tile late via double-buffered wpart (no extra barrier).
// LDS: 2x64KB tile + 10.25KB idx + 0.5KB wpart = 138.5KB, 1 block/CU.
// Expected: dur -> max(DS-pipe ~63us, memory ~55-63us) + tails.

#define N_ROWS   1024
#define D_COLS   100000
#define K_ROUNDS 20
#define SEL_N    256
#define NIDX     (K_ROUNDS * SEL_N)         // 5120
#define CPB      16                         // cols per tile
#define NT       (D_COLS / CPB)             // 6250 tiles (exact)
#define BLOCK    512
#define GRID     256
#define CWAVES   4                          // consumer waves
#define RNDS_PW  (K_ROUNDS / CWAVES)        // 5 rounds per consumer wave
#define NEG_INF  (-3.402823466e+38f)

__global__ __launch_bounds__(BLOCK, 1) void bagmax_kernel(
    const float* __restrict__ inp,
    const int*   __restrict__ indices,
    float*       __restrict__ out)
{
    __shared__ float tile[2][N_ROWS * CPB];                 // 128 KB
    __shared__ __align__(16) unsigned short sidx[NIDX];     // 10.25 KB
    __shared__ float wpart[2][CWAVES][CPB];                 // 512 B

    const int tid = threadIdx.x;
    const int b   = blockIdx.x;
    const int cnt = (NT - b + GRID - 1) / GRID;             // 24 or 25 tiles

    // ---- idx preload: coalesced, u16 transposed to [k][g][j] ----
    for (int i = tid; i < NIDX; i += BLOCK) {
        const int p   = i & 255;
        const int dst = (i & ~255) | ((p & 15) << 4) | (p >> 4);
        sidx[dst] = (unsigned short)indices[i];
    }

    // ---- prologue: ALL 512 threads stage tile 0 into buf0 ----
    {
        const int colbase = b * CPB;
        const int ro = tid >> 2;             // 0..127
        const int c4 = (tid & 3) * 4;
        const float* gp = inp + (size_t)ro * D_COLS + colbase + c4;
        #pragma unroll
        for (int it = 0; it < 8; ++it) {
            const int r = it * 128 + ro;
            const float4 v = *reinterpret_cast<const float4*>(gp + (size_t)it * 128 * D_COLS);
            *reinterpret_cast<float4*>(&tile[0][r * CPB + c4]) = v;
        }
    }
    __syncthreads();

    const bool prod = (tid >= 256);
    const int lane  = tid & 63;
    const int wave  = (tid >> 6) & 3;        // consumer wave 0..3
    const int g     = lane >> 2;             // entry group 0..15
    const int u     = lane & 3;              // col unit

    #pragma unroll 1
    for (int i = 0; i < cnt; ++i) {
        const int cur = i & 1;

        if (prod) {
            // ---- stage tile i+1 into buf[cur^1] while consumers compute ----
            if (i + 1 < cnt) {
                const int ncol = (b + (i + 1) * GRID) * CPB;
                const int ptid = tid - 256;  // 0..255
                const int ro = ptid >> 2;    // 0..63
                const int c4 = (ptid & 3) * 4;
                const float* gp = inp + (size_t)ro * D_COLS + ncol + c4;
                float* tb = &tile[cur ^ 1][0];
                #pragma unroll
                for (int it = 0; it < 16; ++it) {
                    const int r = it * 64 + ro;
                    const float4 v = *reinterpret_cast<const float4*>(gp + (size_t)it * 64 * D_COLS);
                    *reinterpret_cast<float4*>(&tb[r * CPB + c4]) = v;
                }
            }
        } else {
            // ---- finalize tile i-1 (wpart[cur^1] is stable; no race with
            //      this iteration's writes into wpart[cur]) ----
            if (i > 0 && tid < CPB) {
                const int pcol = (b + (i - 1) * GRID) * CPB;
                const float s = wpart[cur ^ 1][0][tid] + wpart[cur ^ 1][1][tid]
                              + wpart[cur ^ 1][2][tid] + wpart[cur ^ 1][3][tid];
                out[pcol + tid] = s * (1.0f / (float)K_ROUNDS);
            }

            // ---- round-major compute on buf[cur] (proven round-9 loop) ----
            const float* tb = &tile[cur][0];
            float4 rsum = make_float4(0.f, 0.f, 0.f, 0.f);
            #pragma unroll
            for (int kk = 0; kk < RNDS_PW; ++kk) {
                const int k = wave * RNDS_PW + kk;

                const uint4* sp = reinterpret_cast<const uint4*>(&sidx[k * SEL_N + g * 16]);
                const uint4 w0 = sp[0];
                const uint4 w1 = sp[1];
                unsigned int e[16];
                e[0]  = w0.x & 0xFFFFu; e[1]  = w0.x >> 16;
                e[2]  = w0.y & 0xFFFFu; e[3]  = w0.y >> 16;
                e[4]  = w0.z & 0xFFFFu; e[5]  = w0.z >> 16;
                e[6]  = w0.w & 0xFFFFu; e[7]  = w0.w >> 16;
                e[8]  = w1.x & 0xFFFFu; e[9]  = w1.x >> 16;
                e[10] = w1.y & 0xFFFFu; e[11] = w1.y >> 16;
                e[12] = w1.z & 0xFFFFu; e[13] = w1.z >> 16;
                e[14] = w1.w & 0xFFFFu; e[15] = w1.w >> 16;

                float4 a0 = make_float4(NEG_INF, NEG_INF, NEG_INF, NEG_INF);
                float4 a1 = a0;
                #pragma unroll
                for (int j = 0; j < 16; j += 2) {
                    const float4 v0 = *reinterpret_cast<const float4*>(&tb[e[j]     * CPB + u * 4]);
                    const float4 v1 = *reinterpret_cast<const float4*>(&tb[e[j + 1] * CPB + u * 4]);
                    a0.x = fmaxf(a0.x, v0.x); a0.y = fmaxf(a0.y, v0.y);
                    a0.z = fmaxf(a0.z, v0.z); a0.w = fmaxf(a0.w, v0.w);
                    a1.x = fmaxf(a1.x, v1.x); a1.y = fmaxf(a1.y, v1.y);
                    a1.z = fmaxf(a1.z, v1.z); a1.w = fmaxf(a1.w, v1.w);
                }
                float4 acc;
                acc.x = fmaxf(a0.x, a1.x); acc.y = fmaxf(a0.y, a1.y);
                acc.z = fmaxf(a0.z, a1.z); acc.w = fmaxf(a0.w, a1.w);

                #pragma unroll
                for (int s = 4; s <= 32; s <<= 1) {
                    acc.x = fmaxf(acc.x, __shfl_xor(acc.x, s, 64));
                    acc.y = fmaxf(acc.y, __shfl_xor(acc.y, s, 64));
                    acc.z = fmaxf(acc.z, __shfl_xor(acc.z, s, 64));
                    acc.w = fmaxf(acc.w, __shfl_xor(acc.w, s, 64));
                }
                rsum.x += acc.x; rsum.y += acc.y; rsum.z += acc.z; rsum.w += acc.w;
            }
            if (g == 0) *reinterpret_cast<float4*>(&wpart[cur][wave][u * 4]) = rsum;
        }
        __syncthreads();
    }

    // ---- epilogue: finalize the last tile ----
    if (tid < CPB) {
        const int pb   = (cnt - 1) & 1;
        const int pcol = (b + (cnt - 1) * GRID) * CPB;
        const float s = wpart[pb][0][tid] + wpart[pb][1][tid]
                      + wpart[pb][2][tid] + wpart[pb][3][tid];
        out[pcol + tid] = s * (1.0f / (float)K_ROUNDS);
    }
}

extern "C" void kernel_launch(void* const* d_in, const int* in_sizes, int n_in,
                              void* d_out, int out_size, void* d_ws, size_t ws_size,
                              hipStream_t stream) {
    const float* inp     = (const float*)d_in[0];
    const int*   indices = (const int*)d_in[1];
    float*       out     = (float*)d_out;

    bagmax_kernel<<<GRID, BLOCK, 0, stream>>>(inp, indices, out);
}